// Round 6
// baseline (375.594 us; speedup 1.0000x reference)
//
#include <hip/hip_runtime.h>
#include <hip/hip_bf16.h>

// int4 weight-only quantized GEMV: out[n] = sum_k A[k] * W[n,k]
//   W[n,k] = (nib(B)[n,k] - 8) * scale[n, k/32] + zero[n, k/32]
// M=1, K=8192, N=16384, GROUP=32.
//
// Dtypes (confirmed R2-R4): A [8192] f32, B [N, K/2] int32 (1 byte payload,
// low nibble = even k), SZ [N, 256, 2] f32, out [N] f32.
//
// R5 post-mortem: r-outer loop gave ~105 us (est; kernel fell out of top-5,
// total 373 us - 268 us fixed harness overhead). Not VALU-bound (~6 us of
// VALU), not BW-saturated (~4.6 B/cyc/CU of ~10). Suspect MLP/issue order:
// only 4 independent B loads per row before dependent compute.
// R6: j-outer / r-inner with register double-buffer on B -> 8 independent
// row-loads (8 KiB/wave) in flight while computing previous chunk; 8 SZ loads
// issued back-to-back per chunk. A chunk a[j] reused 8x consecutively.

#define ROWS 8

__global__ __launch_bounds__(256) void gemv_w4p(
    const float4* __restrict__ A4,   // 8192 f32 = 2048 float4
    const int4*   __restrict__ B,    // [N, 1024] int4 (16B = 4 int32 = 8 k)
    const float2* __restrict__ SZ,   // [N, 256] (scale, zero) f32 pairs
    float* __restrict__ out,         // [N] f32
    int N)
{
    const int t  = threadIdx.x;
    const int n0 = blockIdx.x * ROWS;

    // ---- A slice -> registers, once per block (amortized over ROWS rows) ----
    float a[4][8];
    float sAj[4];
#pragma unroll
    for (int j = 0; j < 4; ++j) {
        const float4 x = A4[2 * t + 512 * j];
        const float4 y = A4[2 * t + 512 * j + 1];
        a[j][0] = x.x; a[j][1] = x.y; a[j][2] = x.z; a[j][3] = x.w;
        a[j][4] = y.x; a[j][5] = y.y; a[j][6] = y.z; a[j][7] = y.w;
        sAj[j] = ((x.x + x.y) + (x.z + x.w)) + ((y.x + y.y) + (y.z + y.w));
    }

    const int4*   Bp = B  + (size_t)n0 * 1024 + t;        // row r at Bp[1024r + 256j]
    const float2* Sp = SZ + (size_t)n0 * 256 + (t >> 2);  // row r at Sp[256r + 64j]

    float acc[ROWS];
#pragma unroll
    for (int r = 0; r < ROWS; ++r) acc[r] = 0.0f;

    // ---- software pipeline over j chunks: prefetch j+1 B while computing j ----
    int4 b[ROWS];
#pragma unroll
    for (int r = 0; r < ROWS; ++r) b[r] = Bp[1024 * r];   // chunk j=0

#pragma unroll
    for (int j = 0; j < 4; ++j) {
        int4 bn[ROWS];
        if (j < 3) {
#pragma unroll
            for (int r = 0; r < ROWS; ++r) bn[r] = Bp[1024 * r + 256 * (j + 1)];
        }

        // SZ for this chunk: 8 independent loads issued back-to-back
        float2 szv[ROWS];
#pragma unroll
        for (int r = 0; r < ROWS; ++r) szv[r] = Sp[256 * r + 64 * j];

#pragma unroll
        for (int r = 0; r < ROWS; ++r) {
            const int bb[4] = { b[r].x, b[r].y, b[r].z, b[r].w };
            float dot = 0.0f;
#pragma unroll
            for (int m = 0; m < 4; ++m) {
                dot = fmaf(a[j][2 * m],     (float)(bb[m] & 0xF),        dot);
                dot = fmaf(a[j][2 * m + 1], (float)((bb[m] >> 4) & 0xF), dot);
            }
            const float s  = szv[r].x;
            const float zz = fmaf(-8.0f, s, szv[r].y);    // z - 8s
            acc[r] = fmaf(s, dot, acc[r]);
            acc[r] = fmaf(zz, sAj[j], acc[r]);
        }

        if (j < 3) {
#pragma unroll
            for (int r = 0; r < ROWS; ++r) b[r] = bn[r];
        }
    }

    // ---- reduce: wave shuffle per row, stage in LDS, one barrier ----
    __shared__ float red[ROWS][4];
    const int lane = t & 63;
    const int w    = t >> 6;
#pragma unroll
    for (int r = 0; r < ROWS; ++r) {
        float v = acc[r];
#pragma unroll
        for (int off = 32; off > 0; off >>= 1)
            v += __shfl_down(v, off, 64);
        if (lane == 0) red[r][w] = v;
    }
    __syncthreads();
    if (t < ROWS) {
        const int n = n0 + t;
        if (n < N)
            out[n] = (red[t][0] + red[t][1]) + (red[t][2] + red[t][3]);
    }
}

extern "C" void kernel_launch(void* const* d_in, const int* in_sizes, int n_in,
                              void* d_out, int out_size, void* d_ws, size_t ws_size,
                              hipStream_t stream) {
    const float4* A4 = (const float4*)d_in[0];   // f32[8192]
    const int4*   B  = (const int4*)d_in[1];     // int32[N, 4096]
    const float2* SZ = (const float2*)d_in[2];   // f32[N, 256, 2]
    float* out = (float*)d_out;                  // f32[N]

    const int N = out_size;                      // 16384
    gemv_w4p<<<N / ROWS, 256, 0, stream>>>(A4, B, SZ, out, N);
}

// Round 7
// 370.942 us; speedup vs baseline: 1.0125x; 1.0125x over previous
//
#include <hip/hip_runtime.h>
#include <hip/hip_bf16.h>

// int4 weight-only quantized GEMV: out[n] = sum_k A[k] * W[n,k]
//   W[n,k] = (nib(B)[n,k] - 8) * scale[n, k/32] + zero[n, k/32]
// M=1, K=8192, N=16384, GROUP=32.
//
// Dtypes (confirmed R2-R4): A [8192] f32, B [N, K/2] int32 (1 byte payload,
// low nibble = even k), SZ [N, 256, 2] f32, out [N] f32.
//
// R6 post-mortem: j-outer "pipeline" was neutral (~105 us kernel) because SZ
// loads issued AFTER the B prefetch forced vmcnt drains of the prefetch.
// R7: single-basic-block structure.
//   - SZ for the block's 8 rows staged to LDS (16 KB) -> steady-state SZ via
//     ds_read (lgkmcnt, independent of vmcnt).
//   - 512 threads; thread t owns int4 indices {t, t+512} of each row.
//     16 independent coalesced B loads issued back-to-back (16 KiB/wave in
//     flight), consumed in issue order -> monotone vmcnt drain, no full stalls.

#define ROWS 8
#define TPB  512

__global__ __launch_bounds__(TPB, 4) void gemv_w4s(
    const float4* __restrict__ A4,   // 8192 f32 = 2048 float4
    const int4*   __restrict__ B,    // [N, 1024] int4 (16B = 4 int32 = 8 k)
    const float2* __restrict__ SZ,   // [N, 256] (scale, zero) f32 pairs
    float* __restrict__ out,         // [N] f32
    int N)
{
    const int t  = threadIdx.x;
    const int n0 = blockIdx.x * ROWS;

    __shared__ float2 sz_s[ROWS * 256];   // 16 KB
    __shared__ float  red[ROWS][8];

    // ---- A slices -> registers (int4 indices t and t+512; k = 8i..8i+7) ----
    float a[2][8];
    float sAj[2];
#pragma unroll
    for (int j = 0; j < 2; ++j) {
        const int i = t + 512 * j;
        const float4 x = A4[2 * i];
        const float4 y = A4[2 * i + 1];
        a[j][0] = x.x; a[j][1] = x.y; a[j][2] = x.z; a[j][3] = x.w;
        a[j][4] = y.x; a[j][5] = y.y; a[j][6] = y.z; a[j][7] = y.w;
        sAj[j] = ((x.x + x.y) + (x.z + x.w)) + ((y.x + y.y) + (y.z + y.w));
    }

    // ---- stage SZ for 8 rows into LDS (coalesced, 4 float2/thread) ----
    {
        const float2* Sp = SZ + (size_t)n0 * 256;
#pragma unroll
        for (int q = 0; q < 4; ++q) {
            const int idx = t + TPB * q;          // 0..2047 = row*256+group
            sz_s[idx] = Sp[idx];
        }
    }
    __syncthreads();

    // ---- issue ALL 16 B loads back-to-back (independent, coalesced) ----
    const int4* Bp = B + (size_t)n0 * 1024 + t;
    int4 b[ROWS][2];
#pragma unroll
    for (int r = 0; r < ROWS; ++r) {
#pragma unroll
        for (int j = 0; j < 2; ++j)
            b[r][j] = Bp[1024 * r + 512 * j];
    }

    // ---- consume in issue order: monotone vmcnt drain ----
    const int g0 = t >> 2;                        // group of int4 t
    float acc[ROWS];
#pragma unroll
    for (int r = 0; r < ROWS; ++r) acc[r] = 0.0f;

#pragma unroll
    for (int r = 0; r < ROWS; ++r) {
#pragma unroll
        for (int j = 0; j < 2; ++j) {
            const float2 sz = sz_s[r * 256 + g0 + 128 * j];  // ds_read, lgkmcnt
            const int bb[4] = { b[r][j].x, b[r][j].y, b[r][j].z, b[r][j].w };
            float dot = 0.0f;
#pragma unroll
            for (int m = 0; m < 4; ++m) {
                dot = fmaf(a[j][2 * m],     (float)(bb[m] & 0xF),        dot);
                dot = fmaf(a[j][2 * m + 1], (float)((bb[m] >> 4) & 0xF), dot);
            }
            const float s  = sz.x;
            const float zz = fmaf(-8.0f, s, sz.y);           // z - 8s
            acc[r] = fmaf(s, dot, acc[r]);
            acc[r] = fmaf(zz, sAj[j], acc[r]);
        }
    }

    // ---- reduce: wave shuffle per row, LDS across 8 waves ----
    const int lane = t & 63;
    const int w    = t >> 6;
#pragma unroll
    for (int r = 0; r < ROWS; ++r) {
        float v = acc[r];
#pragma unroll
        for (int off = 32; off > 0; off >>= 1)
            v += __shfl_down(v, off, 64);
        if (lane == 0) red[r][w] = v;
    }
    __syncthreads();
    if (t < ROWS) {
        const int n = n0 + t;
        if (n < N) {
            float v = 0.0f;
#pragma unroll
            for (int w2 = 0; w2 < 8; ++w2) v += red[t][w2];
            out[n] = v;
        }
    }
}

extern "C" void kernel_launch(void* const* d_in, const int* in_sizes, int n_in,
                              void* d_out, int out_size, void* d_ws, size_t ws_size,
                              hipStream_t stream) {
    const float4* A4 = (const float4*)d_in[0];   // f32[8192]
    const int4*   B  = (const int4*)d_in[1];     // int32[N, 4096]
    const float2* SZ = (const float2*)d_in[2];   // f32[N, 256, 2]
    float* out = (float*)d_out;                  // f32[N]

    const int N = out_size;                      // 16384
    gemv_w4s<<<N / ROWS, TPB, 0, stream>>>(A4, B, SZ, out, N);
}

// Round 8
// 354.827 us; speedup vs baseline: 1.0585x; 1.0454x over previous
//
#include <hip/hip_runtime.h>
#include <hip/hip_bf16.h>

// int4 weight-only quantized GEMV: out[n] = sum_k A[k] * W[n,k]
//   W[n,k] = (nib(B)[n,k] - 8) * scale[n, k/32] + zero[n, k/32]
// M=1, K=8192, N=16384, GROUP=32.
//
// Dtypes (confirmed R2-R4): A [8192] f32, B [N, K/2] int32 (1 byte payload,
// low nibble = even k), SZ [N, 256, 2] f32, out [N] f32.
//
// R5/R6/R7 post-mortem: three different issue structures all ~103 us kernel
// (2.9 TB/s effective reads, no pipe saturated) -> compiler already hoisted
// loads; per-wave MLP is not the lever. Little's law says only ~25-30 lines
// outstanding per CU -> suspected L1/TCP allocate-path (MSHR) cap.
// R8: IDENTICAL structure to R7; ONLY change = B loads are non-temporal
// (global_load_dwordx4 nt, no-allocate streaming). B is read exactly once per
// dispatch; the fill kernel proves non-allocating streams sustain 6.7 TB/s.

#define ROWS 8
#define TPB  512

typedef int ivec4 __attribute__((ext_vector_type(4)));

__global__ __launch_bounds__(TPB, 4) void gemv_w4nt(
    const float4* __restrict__ A4,   // 8192 f32 = 2048 float4
    const ivec4*  __restrict__ B,    // [N, 1024] int4 (16B = 4 int32 = 8 k)
    const float2* __restrict__ SZ,   // [N, 256] (scale, zero) f32 pairs
    float* __restrict__ out,         // [N] f32
    int N)
{
    const int t  = threadIdx.x;
    const int n0 = blockIdx.x * ROWS;

    __shared__ float2 sz_s[ROWS * 256];   // 16 KB
    __shared__ float  red[ROWS][8];

    // ---- A slices -> registers (int4 indices t and t+512; k = 8i..8i+7) ----
    float a[2][8];
    float sAj[2];
#pragma unroll
    for (int j = 0; j < 2; ++j) {
        const int i = t + 512 * j;
        const float4 x = A4[2 * i];
        const float4 y = A4[2 * i + 1];
        a[j][0] = x.x; a[j][1] = x.y; a[j][2] = x.z; a[j][3] = x.w;
        a[j][4] = y.x; a[j][5] = y.y; a[j][6] = y.z; a[j][7] = y.w;
        sAj[j] = ((x.x + x.y) + (x.z + x.w)) + ((y.x + y.y) + (y.z + y.w));
    }

    // ---- stage SZ for 8 rows into LDS (coalesced, 4 float2/thread) ----
    {
        const float2* Sp = SZ + (size_t)n0 * 256;
#pragma unroll
        for (int q = 0; q < 4; ++q) {
            const int idx = t + TPB * q;          // 0..2047 = row*256+group
            sz_s[idx] = Sp[idx];
        }
    }
    __syncthreads();

    // ---- issue ALL 16 B loads back-to-back, NON-TEMPORAL (nt, no-allocate) --
    const ivec4* Bp = B + (size_t)n0 * 1024 + t;
    ivec4 b[ROWS][2];
#pragma unroll
    for (int r = 0; r < ROWS; ++r) {
#pragma unroll
        for (int j = 0; j < 2; ++j)
            b[r][j] = __builtin_nontemporal_load(&Bp[1024 * r + 512 * j]);
    }

    // ---- consume in issue order: monotone vmcnt drain ----
    const int g0 = t >> 2;                        // group of int4 t
    float acc[ROWS];
#pragma unroll
    for (int r = 0; r < ROWS; ++r) acc[r] = 0.0f;

#pragma unroll
    for (int r = 0; r < ROWS; ++r) {
#pragma unroll
        for (int j = 0; j < 2; ++j) {
            const float2 sz = sz_s[r * 256 + g0 + 128 * j];  // ds_read, lgkmcnt
            const int bb[4] = { b[r][j][0], b[r][j][1], b[r][j][2], b[r][j][3] };
            float dot = 0.0f;
#pragma unroll
            for (int m = 0; m < 4; ++m) {
                dot = fmaf(a[j][2 * m],     (float)(bb[m] & 0xF),        dot);
                dot = fmaf(a[j][2 * m + 1], (float)((bb[m] >> 4) & 0xF), dot);
            }
            const float s  = sz.x;
            const float zz = fmaf(-8.0f, s, sz.y);           // z - 8s
            acc[r] = fmaf(s, dot, acc[r]);
            acc[r] = fmaf(zz, sAj[j], acc[r]);
        }
    }

    // ---- reduce: wave shuffle per row, LDS across 8 waves ----
    const int lane = t & 63;
    const int w    = t >> 6;
#pragma unroll
    for (int r = 0; r < ROWS; ++r) {
        float v = acc[r];
#pragma unroll
        for (int off = 32; off > 0; off >>= 1)
            v += __shfl_down(v, off, 64);
        if (lane == 0) red[r][w] = v;
    }
    __syncthreads();
    if (t < ROWS) {
        const int n = n0 + t;
        if (n < N) {
            float v = 0.0f;
#pragma unroll
            for (int w2 = 0; w2 < 8; ++w2) v += red[t][w2];
            out[n] = v;
        }
    }
}

extern "C" void kernel_launch(void* const* d_in, const int* in_sizes, int n_in,
                              void* d_out, int out_size, void* d_ws, size_t ws_size,
                              hipStream_t stream) {
    const float4* A4 = (const float4*)d_in[0];   // f32[8192]
    const ivec4*  B  = (const ivec4*)d_in[1];    // int32[N, 4096]
    const float2* SZ = (const float2*)d_in[2];   // f32[N, 256, 2]
    float* out = (float*)d_out;                  // f32[N]

    const int N = out_size;                      // 16384
    gemv_w4nt<<<N / ROWS, TPB, 0, stream>>>(A4, B, SZ, out, N);
}